// Round 1
// baseline (1664.458 us; speedup 1.0000x reference)
//
#include <hip/hip_runtime.h>

// Problem constants (from reference setup_inputs)
#define BB   4
#define HH   16
#define SS   2048
#define DK   4
#define QTILE 64              // q-rows per block
#define NWAVES 4              // 256 threads
#define KPER  (SS / 64)       // 32 k-elements per lane per row

// One block per (b, h, q-tile). K,V for (b,h) staged in LDS (64 KB),
// reused across QTILE q-rows. One wave per q-row; lane l owns k = l + 64*j.
// attn row kept unnormalized in 32 VGPRs between softmax passes.
__global__ __launch_bounds__(256, 2)
void mha_fullattn_kernel(const float* __restrict__ qry,
                         const float* __restrict__ key,
                         const float* __restrict__ val,
                         const int*   __restrict__ mask,
                         float* __restrict__ out)
{
    __shared__ float4 sK[SS];   // 32 KB
    __shared__ float4 sV[SS];   // 32 KB

    const int tiles = SS / QTILE;           // 32
    const int bh = blockIdx.x / tiles;      // b*H + h
    const int qt = blockIdx.x % tiles;
    const int b  = bh / HH;
    const int tid  = threadIdx.x;
    const int lane = tid & 63;
    const int wave = tid >> 6;

    // ---- stage K,V for this (b,h) into LDS (coalesced float4) ----
    const float4* gK = (const float4*)(key + (size_t)bh * SS * DK);
    const float4* gV = (const float4*)(val + (size_t)bh * SS * DK);
    for (int i = tid; i < SS; i += 256) {
        sK[i] = gK[i];
        sV[i] = gV[i];
    }
    __syncthreads();

    float* outO = out;                               // [B,H,S,4]
    float* outA = out + (size_t)BB * HH * SS * DK;   // [B,H,S,S]

    for (int r = 0; r < QTILE / NWAVES; ++r) {
        const int q_idx = qt * QTILE + r * NWAVES + wave;

        const float4 qv = *(const float4*)(qry + ((size_t)bh * SS + q_idx) * DK);
        const int* mrow = mask + ((size_t)b * SS + q_idx) * SS;

        // ---- pass 1: scores + row max ----
        float s[KPER];
        float mx = -3.0e38f;
        #pragma unroll
        for (int j = 0; j < KPER; ++j) {
            const int kk = lane + 64 * j;
            const float4 kv = sK[kk];
            float sc = qv.x * kv.x + qv.y * kv.y + qv.z * kv.z + qv.w * kv.w;
            sc *= 0.5f;                      // 1/sqrt(4)
            sc = (mrow[kk] == 0) ? -1.0e9f : sc;
            s[j] = sc;
            mx = fmaxf(mx, sc);
        }
        #pragma unroll
        for (int off = 32; off > 0; off >>= 1)
            mx = fmaxf(mx, __shfl_xor(mx, off, 64));

        // ---- exp + row sum (keep unnormalized p in regs) ----
        float sum = 0.0f;
        #pragma unroll
        for (int j = 0; j < KPER; ++j) {
            const float p = __expf(s[j] - mx);   // v_exp_f32
            s[j] = p;
            sum += p;
        }
        #pragma unroll
        for (int off = 32; off > 0; off >>= 1)
            sum += __shfl_xor(sum, off, 64);
        const float rinv = 1.0f / sum;

        // ---- pass 2: write attn (nontemporal) + accumulate P·V ----
        float o0 = 0.f, o1 = 0.f, o2 = 0.f, o3 = 0.f;
        float* arow = outA + ((size_t)bh * SS + q_idx) * SS;
        #pragma unroll
        for (int j = 0; j < KPER; ++j) {
            const int kk = lane + 64 * j;
            const float p = s[j];
            const float4 vv = sV[kk];
            o0 += p * vv.x;
            o1 += p * vv.y;
            o2 += p * vv.z;
            o3 += p * vv.w;
            __builtin_nontemporal_store(p * rinv, arow + kk);
        }
        #pragma unroll
        for (int off = 32; off > 0; off >>= 1) {
            o0 += __shfl_xor(o0, off, 64);
            o1 += __shfl_xor(o1, off, 64);
            o2 += __shfl_xor(o2, off, 64);
            o3 += __shfl_xor(o3, off, 64);
        }
        if (lane == 0) {
            float4 ov = make_float4(o0 * rinv, o1 * rinv, o2 * rinv, o3 * rinv);
            *(float4*)(outO + ((size_t)bh * SS + q_idx) * DK) = ov;
        }
    }
}

extern "C" void kernel_launch(void* const* d_in, const int* in_sizes, int n_in,
                              void* d_out, int out_size, void* d_ws, size_t ws_size,
                              hipStream_t stream) {
    const float* qry  = (const float*)d_in[0];
    const float* key  = (const float*)d_in[1];
    const float* val  = (const float*)d_in[2];
    const int*   mask = (const int*)d_in[3];
    float* out = (float*)d_out;

    const int grid = BB * HH * (SS / QTILE);   // 2048 blocks
    mha_fullattn_kernel<<<grid, 256, 0, stream>>>(qry, key, val, mask, out);
}